// Round 4
// baseline (87.414 us; speedup 1.0000x reference)
//
#include <hip/hip_runtime.h>

#define DIM   4096
#define RANK  16
#define ROWS  4      // rows of x per block
#define NT    512    // kernel A: 8 waves, rank-group = w&3, d-half = w>>2
#define NTB   256    // kernel B: 4 waves, no barriers
#define NWAVE 8

typedef __fp16 f16;
typedef __fp16 f16x2 __attribute__((ext_vector_type(2)));
typedef __fp16 f16x4 __attribute__((ext_vector_type(4)));
typedef __fp16 f16x8 __attribute__((ext_vector_type(8)));
typedef int    int2v  __attribute__((ext_vector_type(2)));
typedef float  f32x4v __attribute__((ext_vector_type(4)));

__device__ __forceinline__ float fdot2f(f16x2 a, f16x2 b, float c) {
    return __builtin_amdgcn_fdot2(a, b, c, false);   // v_dot2_f32_f16
}

// slice i-th f16x2 out of an int4-viewed f16x8; selector folds under full unroll
__device__ __forceinline__ f16x2 h2get(const int4& v, int i) {
    int w;
    switch (i) { case 0: w = v.x; break; case 1: w = v.y; break;
                 case 2: w = v.z; break; default: w = v.w; }
    return __builtin_bit_cast(f16x2, w);
}

// ---- setup kernel: Ut[q][d] = f16(U[d][q]*nw[d]);  Vp[d][q] = f16(V[q][d]) ----
__global__ __launch_bounds__(256) void prep_weights(const float* __restrict__ U,
                                                    const float* __restrict__ nw,
                                                    const float* __restrict__ V,
                                                    f16* __restrict__ Ut,
                                                    f16* __restrict__ Vp) {
    const int d = blockIdx.x * 256 + threadIdx.x;   // 4096 threads total
    const float wv = nw[d];
    const float4* U4 = (const float4*)U;
    const float4 u0 = U4[(size_t)d * 4 + 0];
    const float4 u1 = U4[(size_t)d * 4 + 1];
    const float4 u2 = U4[(size_t)d * 4 + 2];
    const float4 u3 = U4[(size_t)d * 4 + 3];
    Ut[ 0*DIM + d] = (f16)(u0.x*wv); Ut[ 1*DIM + d] = (f16)(u0.y*wv);
    Ut[ 2*DIM + d] = (f16)(u0.z*wv); Ut[ 3*DIM + d] = (f16)(u0.w*wv);
    Ut[ 4*DIM + d] = (f16)(u1.x*wv); Ut[ 5*DIM + d] = (f16)(u1.y*wv);
    Ut[ 6*DIM + d] = (f16)(u1.z*wv); Ut[ 7*DIM + d] = (f16)(u1.w*wv);
    Ut[ 8*DIM + d] = (f16)(u2.x*wv); Ut[ 9*DIM + d] = (f16)(u2.y*wv);
    Ut[10*DIM + d] = (f16)(u2.z*wv); Ut[11*DIM + d] = (f16)(u2.w*wv);
    Ut[12*DIM + d] = (f16)(u3.x*wv); Ut[13*DIM + d] = (f16)(u3.y*wv);
    Ut[14*DIM + d] = (f16)(u3.z*wv); Ut[15*DIM + d] = (f16)(u3.w*wv);
    f16 vq[16];
    #pragma unroll
    for (int q = 0; q < 16; ++q) vq[q] = (f16)V[(size_t)q * DIM + d];  // coalesced per q
    f16x8 lo = { vq[0], vq[1], vq[2], vq[3], vq[4], vq[5], vq[6], vq[7] };
    f16x8 hi = { vq[8], vq[9], vq[10], vq[11], vq[12], vq[13], vq[14], vq[15] };
    f16x8* Vp8 = (f16x8*)Vp;
    Vp8[(size_t)d * 2 + 0] = lo;
    Vp8[(size_t)d * 2 + 1] = hi;
}

// ---- Kernel A: h[row][q] = rstd*S*keep * sum_d x[row][d]*nw[d]*U[d][q] ----
// Pure read pass: x from HBM (plain loads -> leaves x resident in L3 for pass B),
// weights from L2, h (256 KB total) written to workspace. No Phase B.
__global__ __launch_bounds__(NT, 6) void arl_h(
    const float* __restrict__ x,  const f16* __restrict__ Ut,
    const float* __restrict__ S,  f16* __restrict__ hWS)
{
    const int t    = threadIdx.x;
    const int w    = t >> 6;
    const int lane = t & 63;
    const int rg   = w & 3;       // rank group: ranks [4rg, 4rg+4)
    const int dh   = w >> 2;      // d-half: f16x8 chunks [dh*256, dh*256+256)
    const size_t row0 = (size_t)blockIdx.x * ROWS;

    const float4* x4   = (const float4*)(x + row0 * DIM);
    const int4*   Ut16 = (const int4*)Ut;     // [16][512] f16x8-chunks

    __shared__ __align__(16) f16 xh[ROWS * DIM];     // 32 KB fp16 x
    __shared__ float s_ssq[NWAVE][ROWS];
    __shared__ float s_hraw[NWAVE][16];

    // ---- prefetch k=0 Ut operands (latency hides under staging) ----
    int4 u[4];
    {
        const int p0 = dh * 256 + lane;
        #pragma unroll
        for (int ql = 0; ql < 4; ++ql)
            u[ql] = Ut16[(size_t)(rg * 4 + ql) * 512 + p0];
    }

    // ---- Stage x -> LDS (fp16) + fp32 ssq partials ----
    float ssqp[ROWS] = {0.f, 0.f, 0.f, 0.f};
    #pragma unroll
    for (int i = 0; i < 8; ++i) {
        const int idx = i * NT + t;            // 0..4095 float4-chunks
        const int r   = i >> 1;                // row of this chunk (static)
        const float4 val = x4[idx];
        ssqp[r] = fmaf(val.x, val.x, ssqp[r]);
        ssqp[r] = fmaf(val.y, val.y, ssqp[r]);
        ssqp[r] = fmaf(val.z, val.z, ssqp[r]);
        ssqp[r] = fmaf(val.w, val.w, ssqp[r]);
        f16x4 pk;
        pk.x = (f16)val.x; pk.y = (f16)val.y; pk.z = (f16)val.z; pk.w = (f16)val.w;
        ((f16x4*)xh)[idx] = pk;
    }
    __syncthreads();

    // ---- ssq wave-reduce (each thread has partials for all 4 rows) ----
    #pragma unroll
    for (int r = 0; r < ROWS; ++r) {
        float s = ssqp[r];
        #pragma unroll
        for (int off = 32; off >= 1; off >>= 1) s += __shfl_xor(s, off, 64);
        if (lane == 0) s_ssq[w][r] = s;
    }

    // ---- Phase A: wave (rg,dh) accumulates its 4 ranks over its d-half ----
    // hand-pipelined: iter k computes with u (loaded in iter k-1 / prologue)
    // while issuing loads for k+1 under the fdot2 burst.
    float v[16];
    #pragma unroll
    for (int i = 0; i < 16; ++i) v[i] = 0.f;

    #pragma unroll 1
    for (int k = 0; k < 4; ++k) {
        const int pn = dh * 256 + ((k + 1) & 3) * 64 + lane;   // next-iter chunk
        int4 un[4];
        #pragma unroll
        for (int ql = 0; ql < 4; ++ql)
            un[ql] = Ut16[(size_t)(rg * 4 + ql) * 512 + pn];
        const int p = dh * 256 + k * 64 + lane;
        int4 xr[ROWS];
        #pragma unroll
        for (int r = 0; r < ROWS; ++r) xr[r] = ((const int4*)xh)[r * 512 + p];
        #pragma unroll
        for (int i = 0; i < 4; ++i) {
            f16x2 xp[ROWS];
            #pragma unroll
            for (int r = 0; r < ROWS; ++r) xp[r] = h2get(xr[r], i);
            #pragma unroll
            for (int ql = 0; ql < 4; ++ql) {
                const f16x2 up = h2get(u[ql], i);
                #pragma unroll
                for (int r = 0; r < ROWS; ++r)
                    v[r*4+ql] = fdot2f(xp[r], up, v[r*4+ql]);
            }
        }
        #pragma unroll
        for (int ql = 0; ql < 4; ++ql) u[ql] = un[ql];
    }

    // ---- packed wave reduction of v[16] over 64 lanes (proven R4-R9) ----
    #pragma unroll
    for (int i = 0; i < 8; ++i) {
        int a = __float_as_int(v[2*i]);
        int b = __float_as_int(v[2*i+1]);
        int2v pr = __builtin_amdgcn_permlane32_swap(a, b, false, false);
        v[i] = __int_as_float(pr.x) + __int_as_float(pr.y);
    }
    #pragma unroll
    for (int s = 1; s <= 3; ++s) {
        const int off = 32 >> s;
        const int n   = 8 >> s;
        const bool hi = (lane >> (5 - s)) & 1;
        #pragma unroll
        for (int i = 0; i < n; ++i) {
            float lo = v[2*i], hg = v[2*i+1];
            float slo = __shfl_xor(lo, off, 64);
            float shg = __shfl_xor(hg, off, 64);
            v[i] = hi ? (hg + shg) : (lo + slo);
        }
    }
    v[0] += __shfl_xor(v[0], 2, 64);
    v[0] += __shfl_xor(v[0], 1, 64);
    {
        const int idx = ((lane >> 5) & 1) | (((lane >> 4) & 1) << 1)
                      | (((lane >> 3) & 1) << 2) | (((lane >> 2) & 1) << 3);
        if ((lane & 3) == 0) s_hraw[w][idx] = v[0];
    }
    __syncthreads();

    // ---- combine d-halves; fold in rstd[r] and S*keep; write h to workspace ----
    if (t < 64) {
        const int r = t >> 4, q = t & 15;
        const int qg = q >> 2, ql = q & 3;
        const float hs = s_hraw[qg][r * 4 + ql] + s_hraw[qg + 4][r * 4 + ql];
        float tot_ssq = 0.f;
        #pragma unroll
        for (int ww = 0; ww < NWAVE; ++ww) tot_ssq += s_ssq[ww][r];
        const float rstd = rsqrtf(tot_ssq * (1.0f / DIM) + 1e-6f);
        float tot = 0.f;
        #pragma unroll
        for (int i = 0; i < RANK; ++i) tot += fabsf(S[i]);
        const float denom = fmaxf(tot, 1e-8f);
        float cum = 0.f, se = 0.f;
        #pragma unroll
        for (int i = 0; i < RANK; ++i) {
            if (i == q) se = ((cum / denom) < 0.95f) ? S[i] : 0.f;
            cum += fabsf(S[i]);
        }
        hWS[(row0 + r) * RANK + q] = (f16)(hs * se * rstd);   // 128 B/block, contiguous
    }
}

// ---- Kernel B: out[row][d] = x[row][d] + gamma[d] * sum_q h[row][q]*Vp[d][q] ----
// Barrier-free streaming pass: h via L1-broadcast loads, x re-read is L3-hot
// (left there by kernel A; nontemporal OUT stores avoid evicting it), out -> HBM.
__global__ __launch_bounds__(NTB, 6) void arl_apply(
    const float* __restrict__ x,  const f16* __restrict__ hWS,
    const f16* __restrict__ Vp,   const float* __restrict__ gamma,
    float* __restrict__ out)
{
    const int t = threadIdx.x;
    const size_t row0 = (size_t)blockIdx.x * ROWS;

    const float4* x4   = (const float4*)(x + row0 * DIM);
    float4*       out4 = (float4*)(out + row0 * DIM);
    const int4*   Vp16 = (const int4*)Vp;     // [4096][2]
    const float4* g4   = (const float4*)gamma;

    // h for this block's 4 rows: 2 int4 per row, same addresses across the
    // whole block -> L1 broadcast
    f16x2 hp[ROWS][8];
    #pragma unroll
    for (int r = 0; r < ROWS; ++r) {
        const int4* hr = (const int4*)(hWS + (row0 + r) * RANK);
        const int4 a = hr[0];
        const int4 b = hr[1];
        #pragma unroll
        for (int i = 0; i < 4; ++i) {
            hp[r][i]     = h2get(a, i);
            hp[r][4 + i] = h2get(b, i);
        }
    }

    #pragma unroll 1
    for (int j = 0; j < 4; ++j) {
        const int c = j * NTB + t;                // float4 column 0..1023
        float4 xr[ROWS];                          // residual: L3-hot, issue early
        #pragma unroll
        for (int r = 0; r < ROWS; ++r) xr[r] = x4[(size_t)r * (DIM/4) + c];
        const float4 g = g4[c];
        float acc[ROWS][4];
        #pragma unroll
        for (int r = 0; r < ROWS; ++r)
            #pragma unroll
            for (int jj = 0; jj < 4; ++jj) acc[r][jj] = 0.f;
        #pragma unroll
        for (int jj = 0; jj < 4; ++jj) {
            const int dd = c * 4 + jj;
            const int4 v0 = Vp16[(size_t)dd * 2 + 0];
            const int4 v1 = Vp16[(size_t)dd * 2 + 1];
            #pragma unroll
            for (int r = 0; r < ROWS; ++r) {
                float a = acc[r][jj];
                #pragma unroll
                for (int i = 0; i < 4; ++i)
                    a = fdot2f(hp[r][i], h2get(v0, i), a);
                #pragma unroll
                for (int i = 0; i < 4; ++i)
                    a = fdot2f(hp[r][4+i], h2get(v1, i), a);
                acc[r][jj] = a;
            }
        }
        #pragma unroll
        for (int r = 0; r < ROWS; ++r) {
            float4 o;
            o.x = fmaf(g.x, acc[r][0], xr[r].x);
            o.y = fmaf(g.y, acc[r][1], xr[r].y);
            o.z = fmaf(g.z, acc[r][2], xr[r].z);
            o.w = fmaf(g.w, acc[r][3], xr[r].w);
            __builtin_nontemporal_store(*(const f32x4v*)&o,
                                        (f32x4v*)(out4 + (size_t)r * (DIM/4) + c));
        }
    }
}

extern "C" void kernel_launch(void* const* d_in, const int* in_sizes, int n_in,
                              void* d_out, int out_size, void* d_ws, size_t ws_size,
                              hipStream_t stream) {
    (void)in_sizes; (void)n_in; (void)ws_size;
    const float* x  = (const float*)d_in[0];
    const float* U  = (const float*)d_in[1];
    const float* S  = (const float*)d_in[2];
    const float* V  = (const float*)d_in[3];
    const float* nw = (const float*)d_in[4];
    const float* g  = (const float*)d_in[5];
    float* out = (float*)d_out;
    f16* Ut  = (f16*)d_ws;                                    // 128 KB
    f16* Vp  = (f16*)((char*)d_ws + 128 * 1024);              // 128 KB
    f16* hWS = (f16*)((char*)d_ws + 256 * 1024);              // 256 KB (8192*16*2B)

    hipLaunchKernelGGL(prep_weights, dim3(DIM / 256), dim3(256), 0, stream,
                       U, nw, V, Ut, Vp);

    const int rows = out_size / DIM;           // 8192
    const int grid = rows / ROWS;              // 2048
    hipLaunchKernelGGL(arl_h, dim3(grid), dim3(NT), 0, stream,
                       x, Ut, S, hWS);
    hipLaunchKernelGGL(arl_apply, dim3(grid), dim3(NTB), 0, stream,
                       x, hWS, Vp, g, out);
}

// Round 5
// 73.548 us; speedup vs baseline: 1.1885x; 1.1885x over previous
//
#include <hip/hip_runtime.h>

#define DIM   4096
#define RANK  16
#define BM    16     // rows per block = MFMA M
#define NT    512    // 8 waves
#define NWAVE 8
#define KSLICE (DIM/NWAVE)   // 512 k per wave in phase A
#define NKB   (KSLICE/32)    // 16 MFMA K-steps per wave
#define NCB   (DIM/16/NWAVE) // 32 out col-blocks per wave in phase B

typedef __fp16 f16;
typedef __fp16 half4 __attribute__((ext_vector_type(4)));
typedef __fp16 half8 __attribute__((ext_vector_type(8)));
typedef float  floatx4 __attribute__((ext_vector_type(4)));

// ---- prep: weights in exact MFMA fragment order ----
// A/B fragment mapping (16x16xK): lane&15 = row(A)/col(B), lane>>4 = k-block.
// Ub[kb][l][e] = nw[k]*U[k][l&15],          k = kb*32 + (l>>4)*8 + e   (128 KB)
// Vb[cb][l][e] = V[(l>>4)*4 + e][cb*16+l&15]                           (128 KB)
__global__ __launch_bounds__(256) void prep_weights(const float* __restrict__ U,
    const float* __restrict__ nw, const float* __restrict__ V,
    f16* __restrict__ Ub, f16* __restrict__ Vb)
{
    const int i   = blockIdx.x * 256 + threadIdx.x;   // 0..16383
    const int l   = i & 63;
    const int n   = l & 15;
    const int blk = l >> 4;
    if (i < 8192) {                     // Ub: 128 kb-steps x 64 lanes
        const int kb = i >> 6;
        half8 u;
        #pragma unroll
        for (int e = 0; e < 8; ++e) {
            const int k = kb * 32 + blk * 8 + e;
            u[e] = (f16)(nw[k] * U[(size_t)k * RANK + n]);
        }
        *(half8*)(Ub + (size_t)i * 8) = u;      // 16 B coalesced
    }
    {                                   // Vb: 256 col-blocks x 64 lanes
        const int cb = i >> 6;
        half4 v;
        #pragma unroll
        for (int e = 0; e < 4; ++e) {
            const int k = blk * 4 + e;
            v[e] = (f16)V[(size_t)k * DIM + cb * 16 + n];
        }
        *(half4*)(Vb + (size_t)i * 4) = v;      // 8 B coalesced
    }
}

// ---- fused kernel: MFMA phase A (x.U), tiny reduce, MFMA phase B (h.V) ----
// No x staging LDS, no cross-lane dot reduction: MFMA C-fragments carry the
// rank dots. Only 2 barriers per block around a 9 KB h/ssq combine.
__global__ __launch_bounds__(NT, 4) void arl_fused(
    const float* __restrict__ x,  const f16* __restrict__ Ub,
    const f16* __restrict__ Vb,   const float* __restrict__ S,
    const float* __restrict__ gamma, float* __restrict__ out)
{
    const int t   = threadIdx.x;
    const int w   = t >> 6;
    const int l   = t & 63;
    const int n   = l & 15;     // row (A-frag) / col (B,D-frags)
    const int blk = l >> 4;     // k-block / D row-group
    const size_t row0 = (size_t)blockIdx.x * BM;

    __shared__ float s_hacc[NWAVE][16][17];   // +1 pad: conflict-free combine
    __shared__ float s_ssq[NWAVE][16];
    __shared__ __align__(8) f16 s_hh[16][16];

    // ================= Phase A: acc[m][q] += x[m][k]*U'[k][q] =================
    // lane reads row (row0+n), k = w*512 + kb*32 + blk*8 + [0,8)  -> 32 B/lane
    const float* xlane = x + (row0 + n) * DIM + w * KSLICE + blk * 8;
    const half8* UbW   = (const half8*)Ub + (size_t)w * NKB * 64 + l;

    floatx4 acc = {0.f, 0.f, 0.f, 0.f};
    float ssq = 0.f;

    float4 xa0 = *(const float4*)(xlane);
    float4 xa1 = *(const float4*)(xlane + 4);
    half8  ub  = UbW[0];

    #pragma unroll 1
    for (int kb = 0; kb < NKB; ++kb) {
        const int kn = (kb + 1) & (NKB - 1);          // wraps on last iter (harmless)
        float4 nx0 = *(const float4*)(xlane + kn * 32);
        float4 nx1 = *(const float4*)(xlane + kn * 32 + 4);
        half8  nub = UbW[(size_t)kn * 64];
        // fp32 ssq from the exact x values
        ssq = fmaf(xa0.x, xa0.x, ssq); ssq = fmaf(xa0.y, xa0.y, ssq);
        ssq = fmaf(xa0.z, xa0.z, ssq); ssq = fmaf(xa0.w, xa0.w, ssq);
        ssq = fmaf(xa1.x, xa1.x, ssq); ssq = fmaf(xa1.y, xa1.y, ssq);
        ssq = fmaf(xa1.z, xa1.z, ssq); ssq = fmaf(xa1.w, xa1.w, ssq);
        // f16 A-fragment
        half8 a;
        a[0] = (f16)xa0.x; a[1] = (f16)xa0.y; a[2] = (f16)xa0.z; a[3] = (f16)xa0.w;
        a[4] = (f16)xa1.x; a[5] = (f16)xa1.y; a[6] = (f16)xa1.z; a[7] = (f16)xa1.w;
        acc = __builtin_amdgcn_mfma_f32_16x16x32_f16(a, ub, acc, 0, 0, 0);
        xa0 = nx0; xa1 = nx1; ub = nub;
    }

    // ssq: sum the 4 k-block lane groups sharing a row (lanes l, l^16, l^32, l^48)
    ssq += __shfl_xor(ssq, 16, 64);
    ssq += __shfl_xor(ssq, 32, 64);
    if (l < 16) s_ssq[w][l] = ssq;

    // spill C-fragment: D[m = blk*4+j][q = n]
    #pragma unroll
    for (int j = 0; j < 4; ++j) s_hacc[w][blk * 4 + j][n] = acc[j];
    __syncthreads();

    // ============ combine waves; fold rstd + S*keep; publish h (f16) ============
    if (t < 256) {
        const int m = t >> 4, q = t & 15;
        float hsum = 0.f, tssq = 0.f;
        #pragma unroll
        for (int ww = 0; ww < NWAVE; ++ww) {
            hsum += s_hacc[ww][m][q];
            tssq += s_ssq[ww][m];
        }
        const float rstd = rsqrtf(tssq * (1.0f / DIM) + 1e-6f);
        float tot = 0.f;
        #pragma unroll
        for (int i = 0; i < RANK; ++i) tot += fabsf(S[i]);
        const float denom = fmaxf(tot, 1e-8f);
        float cum = 0.f, se = 0.f;
        #pragma unroll
        for (int i = 0; i < RANK; ++i) {
            if (i == q) se = ((cum / denom) < 0.95f) ? S[i] : 0.f;
            cum += fabsf(S[i]);
        }
        s_hh[m][q] = (f16)(hsum * se * rstd);
    }
    __syncthreads();

    // ================= Phase B: out = x + gamma * (h . V) =================
    // A-frag (h) is loop-invariant: lane holds h[n][blk*4 .. +4)
    const half4 ah = *(const half4*)&s_hh[n][blk * 4];
    const half4* Vb4 = (const half4*)Vb;
    const floatx4 zero = {0.f, 0.f, 0.f, 0.f};

    #pragma unroll 2
    for (int i = 0; i < NCB; ++i) {
        const int cb = w * NCB + i;
        const int c0 = cb * 16;
        const half4 bv = Vb4[(size_t)cb * 64 + l];          // 8 B coalesced, L2-hot
        floatx4 d = __builtin_amdgcn_mfma_f32_16x16x16f16(ah, bv, zero, 0, 0, 0);
        const float g = gamma[c0 + n];
        const float* xr  = x   + (row0 + blk * 4) * DIM + c0 + n;   // L3-hot (phase A)
        float*       orr = out + (row0 + blk * 4) * DIM + c0 + n;
        #pragma unroll
        for (int j = 0; j < 4; ++j) {
            const float xv = xr[(size_t)j * DIM];
            __builtin_nontemporal_store(fmaf(g, d[j], xv), orr + (size_t)j * DIM);
        }
    }
}

extern "C" void kernel_launch(void* const* d_in, const int* in_sizes, int n_in,
                              void* d_out, int out_size, void* d_ws, size_t ws_size,
                              hipStream_t stream) {
    (void)in_sizes; (void)n_in; (void)ws_size;
    const float* x  = (const float*)d_in[0];
    const float* U  = (const float*)d_in[1];
    const float* S  = (const float*)d_in[2];
    const float* V  = (const float*)d_in[3];
    const float* nw = (const float*)d_in[4];
    const float* g  = (const float*)d_in[5];
    float* out = (float*)d_out;
    f16* Ub = (f16*)d_ws;                          // 128 KB fragment-order U'
    f16* Vb = (f16*)((char*)d_ws + 128 * 1024);    // 128 KB fragment-order V

    hipLaunchKernelGGL(prep_weights, dim3(64), dim3(256), 0, stream,
                       U, nw, V, Ub, Vb);

    const int rows = out_size / DIM;               // 8192
    const int grid = rows / BM;                    // 512
    hipLaunchKernelGGL(arl_fused, dim3(grid), dim3(NT), 0, stream,
                       x, Ub, Vb, S, g, out);
}